// Round 16
// baseline (77.445 us; speedup 1.0000x reference)
//
#include <hip/hip_runtime.h>
#include <hip/hip_bf16.h>

#define DM 1024
#define HID 64
#define NSTEP 6
#define RSTEP (1.0f/6.0f)

using short8  = __attribute__((ext_vector_type(8))) short;
using short4v = __attribute__((ext_vector_type(4))) short;
using f32x4   = __attribute__((ext_vector_type(4))) float;

// workspace byte offsets
#define WS_W1P 0          // 1024x64 bf16 packed A-frags (131072 B)
#define WS_W2P 131072     // 64x1024 bf16 packed A-frags (131072 B)
#define WS_GP  262144     // 64x64 bf16 packed A-frags (8192 B)
#define WS_U   270336     // 64 f32  (u = b2 @ W1k)
#define WS_VST 270592     // 24x64 f32 affine stage consts (6144 B)
#define WS_HU  276736     // 64 f32  (h*u) (256 B)

// LDS (block-shared, total 17408 B -> 4 blocks/CU easily)
#define L_H0  0           // H ping  [16][72] bf16, pitch 144 (2304)
#define L_H1  2304        // H pong
#define L_HB  4608        // Hb / bf16(S) buffer
#define L_VST 6912        // VST staged (6144)
#define L_HU  13056       // h*u staged (256)
#define L_B2  13312       // b2 staged f32[1024] (4096)
#define LDS_TOTAL 17408
#define HP 144

// LDS-only barrier: order LDS ops, do NOT drain vmcnt (global loads stay
// in flight across barriers).
#define BAR() asm volatile("s_waitcnt lgkmcnt(0)\n\ts_barrier" ::: "memory")

__device__ __forceinline__ short f2bf(float f) {   // RNE via HW cvt
    __hip_bfloat16 h = __float2bfloat16(f);
    short s;
    __builtin_memcpy(&s, &h, 2);
    return s;
}
__device__ __forceinline__ float ftanh(float x) {
    x = fminf(fmaxf(x, -10.f), 10.f);
    float e = __expf(2.f * x);
    return __fdividef(e - 1.f, e + 1.f);
}

// ---------------- prep: pack weights + precompute stage tables ----------------
__global__ void k_prep(const float* __restrict__ W1, const float* __restrict__ W2,
                       const float* __restrict__ b1, const float* __restrict__ b2,
                       short* __restrict__ W1P, short* __restrict__ W2P,
                       short* __restrict__ GP, float* __restrict__ U,
                       float* __restrict__ VST, float* __restrict__ HU) {
    __shared__ float red[4][64];
    int b = blockIdx.x;
    int t = threadIdx.x;           // 256 threads
    int l = t & 63, q4 = t >> 6;
    if (b < 32) {                  // W1P: kk = b, c = q4
        int kk = b, c = q4;
        int col = c * 16 + (l & 15);
        int kb = kk * 32 + ((l >> 4) << 3);
        short8 v;
        #pragma unroll
        for (int i = 0; i < 8; ++i) v[i] = f2bf(W1[(kb + i) * HID + col]);
        *(short8*)(W1P + (((kk * 4 + c) * 64) + l) * 8) = v;
    } else if (b < 64) {           // W2P: unit = (b-32)*4 + q4
        int unit = (b - 32) * 4 + q4;
        int kk2 = unit >> 6, ct = unit & 63;
        int col = ct * 16 + (l & 15);
        int kb = kk2 * 32 + ((l >> 4) << 3);
        short8 v;
        #pragma unroll
        for (int i = 0; i < 8; ++i) v[i] = f2bf(W2[(kb + i) * DM + col]);
        *(short8*)(W2P + (((kk2 * 64 + ct) * 64) + l) * 8) = v;
    } else if (b < 128) {          // G[j][i] = sum_d W2[j][d]*W1[d][i]; j = b-64
        int j = b - 64;
        float acc = 0.f;
        #pragma unroll 8
        for (int d = q4 * 256; d < q4 * 256 + 256; ++d)
            acc += W2[j * DM + d] * W1[d * HID + l];
        red[q4][l] = acc;
        __syncthreads();
        if (t < 64) {
            float a = red[0][l] + red[1][l] + red[2][l] + red[3][l];
            int kk = j >> 5, lk = (j >> 3) & 3, ii = j & 7, c = l >> 4, lo = l & 15;
            GP[(((kk * 4 + c) * 64) + lk * 16 + lo) * 8 + ii] = f2bf(a);
        }
    } else {                       // u = b2@W1k, HU = h*u, VST table
        float acc = 0.f;
        #pragma unroll 8
        for (int d = q4 * 256; d < q4 * 256 + 256; ++d)
            acc += b2[d] * W1[d * HID + l];
        red[q4][l] = acc;
        __syncthreads();
        if (t < 64) {
            float uu = red[0][l] + red[1][l] + red[2][l] + red[3][l];
            U[l] = uu;
            HU[l] = RSTEP * uu;
            float b1l = b1[l];
            float wtl = W1[DM * HID + l];        // time row of W1
            #pragma unroll
            for (int s6 = 0; s6 < 6; ++s6) {
                float ts = RSTEP * (float)s6;
                float tm = ts + 0.5f * RSTEP;
                float vmid = b1l + tm * wtl + 0.5f * RSTEP * uu;
                VST[(s6 * 4 + 0) * 64 + l] = b1l + ts * wtl;
                VST[(s6 * 4 + 1) * 64 + l] = vmid;
                VST[(s6 * 4 + 2) * 64 + l] = vmid;
                VST[(s6 * 4 + 3) * 64 + l] = b1l + (ts + RSTEP) * wtl + RSTEP * uu;
            }
        }
    }
}

// epilogue ping-pong macros (named buffers — rule-#20-safe; internals
// prefixed epc_/acc to avoid capturing caller identifiers — R15 bug)
#define EPL(Wa,Wb,Wc,Wd,Xa,Xb,P) \
    Wa = w2p8[(P) * 64 + lane];        Wb = w2p8[((P) + 64) * 64 + lane]; \
    Wc = w2p8[((P) + 1) * 64 + lane];  Wd = w2p8[((P) + 65) * 64 + lane]; \
    Xa = *(const f32x4*)(xrow + (P) * 16 + (hq << 2)); \
    Xb = *(const f32x4*)(xrow + ((P) + 1) * 16 + (hq << 2));

#define EPC(Wa,Wb,Wc,Wd,Xa,Xb,P) { \
    f32x4 acc0 = (f32x4){0.f,0.f,0.f,0.f}, acc1 = (f32x4){0.f,0.f,0.f,0.f}; \
    acc0 = __builtin_amdgcn_mfma_f32_16x16x32_bf16(Wa, sb0, acc0, 0, 0, 0); \
    acc0 = __builtin_amdgcn_mfma_f32_16x16x32_bf16(Wb, sb1, acc0, 0, 0, 0); \
    acc1 = __builtin_amdgcn_mfma_f32_16x16x32_bf16(Wc, sb0, acc1, 0, 0, 0); \
    acc1 = __builtin_amdgcn_mfma_f32_16x16x32_bf16(Wd, sb1, acc1, 0, 0, 0); \
    f32x4 epc_bv0 = *(const f32x4*)(smem + L_B2 + ((P) * 16 + (hq << 2)) * 4); \
    f32x4 epc_bv1 = *(const f32x4*)(smem + L_B2 + (((P) + 1) * 16 + (hq << 2)) * 4); \
    f32x4 epc_n0, epc_n1; \
    for (int j = 0; j < 4; ++j) { epc_n0[j] = Xa[j] + acc0[j] + epc_bv0[j]; \
                                  epc_n1[j] = Xb[j] + acc1[j] + epc_bv1[j]; } \
    *(f32x4*)(orow + (P) * 16 + (hq << 2)) = epc_n0; \
    *(f32x4*)(orow + ((P) + 1) * 16 + (hq << 2)) = epc_n1; }

// ---------------- fused RK4 neural-ODE kernel ----------------
// R12's 4-wave distributed stages x R14's deep memory endpoints.
// Block: 256 thr (4 waves), 16 rows, grid 1024 -> 4 blocks/CU = 16 waves/CU
// (4/SIMD: every phase gets 4-deep wave overlap — R14 had 1/SIMD).
// Algebra (R12/R13-proven): incremental sz (sz' = sz + Hb@G + h*u; GEMM1
// once in prologue) + deferred z (z_T = x + S@W2 + b2, S accumulated f32,
// one epilogue GEMM). Wave w owns hid c-tile w in stages (1/4 the tanh
// chain of R14's all-c waves); H0/H1/HB triple buffer, 4 lgkm-only
// BARs/step (race-free: eval3's BAR precedes both the HB readers and the
// next step's H0 writer).
// Prologue: 16-deep X load bursts/wave (R14); 4 waves share row lines->L1.
// Epilogue: 16 ct/wave, 2-ct ping-pong one batch ahead; b2 from LDS.
// MFMA: A = packed weights (M = out-col), B = z/H rows (N = row).
// D: m=(lane>>4)*4+reg (col), n=lane&15 (row).
// ALLOCATION: amdgpu_waves_per_eu(2,4) — only attr honored at VGPR<=128
// without spill (14-round ledger). Peak live-set ~95 regs (prologue burst).
__global__ __launch_bounds__(256) __attribute__((amdgpu_waves_per_eu(2, 4)))
void k_ode(
        const float* __restrict__ X, const float* __restrict__ b2,
        const short* __restrict__ W1P, const short* __restrict__ W2P,
        const short* __restrict__ GP, const float* __restrict__ VST,
        const float* __restrict__ HU, float* __restrict__ OUT) {
    extern __shared__ char smem[];
    const int t = threadIdx.x;
    const int lane = t & 63;
    const int w = t >> 6;                    // 0..3 = c-tile in stages
    const int hq = lane >> 4;
    const int l15 = lane & 15;
    const int hcol0 = w * 16 + hq * 4;       // stage hid-col base
    const size_t row0 = (size_t)blockIdx.x * 16;
    const float* xrow = X + (row0 + l15) * DM;

    // ---- stage consts into LDS (b2, VST, HU) ----
    *(f32x4*)(smem + L_B2 + t * 16) = *(const f32x4*)(b2 + t * 4);
    *(f32x4*)(smem + L_VST + t * 16) = *(const f32x4*)(VST + t * 4);
    if (t < 128)
        *(f32x4*)(smem + L_VST + 4096 + t * 16) = *(const f32x4*)(VST + 1024 + t * 4);
    else if (t < 144)
        *(f32x4*)(smem + L_HU + (t - 128) * 16) = *(const f32x4*)(HU + (t - 128) * 4);

    // pinned G A-frags for own c-tile
    short8 gf0 = *(const short8*)(GP + (w * 64 + lane) * 8);
    short8 gf1 = *(const short8*)(GP + ((4 + w) * 64 + lane) * 8);

    // ---- prologue GEMM1 (once): sz = x @ W1k for c-tile w; 16-deep bursts
    f32x4 sz = (f32x4){0.f, 0.f, 0.f, 0.f};
    {
        const short8* wp = (const short8*)W1P;
        #pragma unroll
        for (int B = 0; B < 4; ++B) {
            f32x4 lo[8], hi[8];              // the 16-deep burst
            #pragma unroll
            for (int i = 0; i < 8; ++i) {
                const float* xp = xrow + ((B * 8 + i) << 5) + (hq << 3);
                lo[i] = *(const f32x4*)(xp);
                hi[i] = *(const f32x4*)(xp + 4);
            }
            #pragma unroll
            for (int i = 0; i < 8; ++i) {
                int kk = B * 8 + i;
                short8 zf;
                #pragma unroll
                for (int j = 0; j < 4; ++j) { zf[j] = f2bf(lo[i][j]); zf[4 + j] = f2bf(hi[i][j]); }
                sz = __builtin_amdgcn_mfma_f32_16x16x32_bf16(
                         wp[(kk * 4 + w) * 64 + lane], zf, sz, 0, 0, 0);
            }
        }
    }
    BAR();   // covers LDS const staging; prologue MFMA needs no sync

    f32x4 ssum = (f32x4){0.f, 0.f, 0.f, 0.f};

    for (int s = 0; s < NSTEP; ++s) {
        f32x4 hsum;

        // eval 0: H = tanh(sz + VST[s][0]) -> H0 (own c-tile)
        {
            f32x4 vst = *(const f32x4*)(smem + L_VST + (s * 4 + 0) * 256 + hcol0 * 4);
            short4v hc;
            #pragma unroll
            for (int j = 0; j < 4; ++j) {
                float h = ftanh(sz[j] + vst[j]);
                hsum[j] = h;
                hc[j] = f2bf(h);
            }
            *(short4v*)(smem + L_H0 + l15 * HP + hcol0 * 2) = hc;
        }
        BAR();

        // evals 1..3: dd = H@G; H' = tanh(sz + c_e*dd + VST[s][e])
        #pragma unroll
        for (int e = 1; e < 4; ++e) {
            const float ce = (e == 3) ? RSTEP : (0.5f * RSTEP);
            const float we = (e == 3) ? 1.f : 2.f;
            const int rbuf = (e == 2) ? L_H1 : L_H0;     // e1:H0->H1, e2:H1->H0, e3:H0->HB
            const int wbuf = (e == 1) ? L_H1 : ((e == 2) ? L_H0 : L_HB);

            short8 hf0 = *(const short8*)(smem + rbuf + l15 * HP + (hq << 4));
            short8 hf1 = *(const short8*)(smem + rbuf + l15 * HP + 64 + (hq << 4));
            f32x4 dd = (f32x4){0.f, 0.f, 0.f, 0.f};
            dd = __builtin_amdgcn_mfma_f32_16x16x32_bf16(gf0, hf0, dd, 0, 0, 0);
            dd = __builtin_amdgcn_mfma_f32_16x16x32_bf16(gf1, hf1, dd, 0, 0, 0);
            f32x4 vst = *(const f32x4*)(smem + L_VST + (s * 4 + e) * 256 + hcol0 * 4);
            short4v hc;
            #pragma unroll
            for (int j = 0; j < 4; ++j) {
                float h = ftanh(sz[j] + ce * dd[j] + vst[j]);
                hsum[j] += we * h;
                if (e < 3) {
                    hc[j] = f2bf(h);
                } else {
                    ssum[j] += hsum[j] * (RSTEP / 6.f);
                    hc[j] = (s < NSTEP - 1) ? f2bf(hsum[j] * (RSTEP / 6.f))
                                            : f2bf(ssum[j]);
                }
            }
            *(short4v*)(smem + wbuf + l15 * HP + hcol0 * 2) = hc;
            BAR();
        }

        // sz update: sz += Hb@G + h*u (HB readers precede next eval3's
        // writes by >=2 BARs; next eval0 writes H0, whose last readers
        // (eval3) passed the BAR above -> race-free)
        if (s < NSTEP - 1) {
            short8 hb0 = *(const short8*)(smem + L_HB + l15 * HP + (hq << 4));
            short8 hb1 = *(const short8*)(smem + L_HB + l15 * HP + 64 + (hq << 4));
            f32x4 d = (f32x4){0.f, 0.f, 0.f, 0.f};
            d = __builtin_amdgcn_mfma_f32_16x16x32_bf16(gf0, hb0, d, 0, 0, 0);
            d = __builtin_amdgcn_mfma_f32_16x16x32_bf16(gf1, hb1, d, 0, 0, 0);
            f32x4 hu4 = *(const f32x4*)(smem + L_HU + hcol0 * 4);
            #pragma unroll
            for (int j = 0; j < 4; ++j)
                sz[j] += d[j] + hu4[j];
        }
    }

    // ---- epilogue: z_T = x + S@W2 + b2; wave w -> ct [w*16, w*16+16),
    // 2-ct ping-pong one batch ahead. HB holds bf16(S) (last eval3, BAR'd).
    {
        short8 sb0 = *(const short8*)(smem + L_HB + l15 * HP + (hq << 4));
        short8 sb1 = *(const short8*)(smem + L_HB + l15 * HP + 64 + (hq << 4));
        const short8* w2p8 = (const short8*)W2P;
        float* orow = OUT + (row0 + l15) * DM;
        const int ctbase = w * 16;

        short8 wA0, wA1, wA2, wA3; f32x4 xA0, xA1;
        short8 wB0, wB1, wB2, wB3; f32x4 xB0, xB1;
        EPL(wA0, wA1, wA2, wA3, xA0, xA1, ctbase)
        #pragma unroll
        for (int p = 0; p < 16; p += 4) {
            EPL(wB0, wB1, wB2, wB3, xB0, xB1, ctbase + p + 2)
            EPC(wA0, wA1, wA2, wA3, xA0, xA1, ctbase + p)
            if (p + 4 < 16) { EPL(wA0, wA1, wA2, wA3, xA0, xA1, ctbase + p + 4) }
            EPC(wB0, wB1, wB2, wB3, xB0, xB1, ctbase + p + 2)
        }
    }
}

extern "C" void kernel_launch(void* const* d_in, const int* in_sizes, int n_in,
                              void* d_out, int out_size, void* d_ws, size_t ws_size,
                              hipStream_t stream) {
    (void)in_sizes; (void)n_in; (void)out_size; (void)ws_size;
    const float* X  = (const float*)d_in[0];
    const float* W1 = (const float*)d_in[1];
    const float* b1 = (const float*)d_in[2];
    const float* W2 = (const float*)d_in[3];
    const float* b2 = (const float*)d_in[4];
    float* OUT = (float*)d_out;
    short* W1P = (short*)((char*)d_ws + WS_W1P);
    short* W2P = (short*)((char*)d_ws + WS_W2P);
    short* GP  = (short*)((char*)d_ws + WS_GP);
    float* U   = (float*)((char*)d_ws + WS_U);
    float* VST = (float*)((char*)d_ws + WS_VST);
    float* HU  = (float*)((char*)d_ws + WS_HU);

    k_prep<<<129, 256, 0, stream>>>(W1, W2, b1, b2, W1P, W2P, GP, U, VST, HU);
    k_ode<<<1024, 256, LDS_TOTAL, stream>>>(X, b2, W1P, W2P, GP, VST, HU, OUT);
}

// Round 17
// 76.812 us; speedup vs baseline: 1.0082x; 1.0082x over previous
//
#include <hip/hip_runtime.h>
#include <hip/hip_bf16.h>

#define DM 1024
#define HID 64
#define NSTEP 6
#define RSTEP (1.0f/6.0f)

using short8  = __attribute__((ext_vector_type(8))) short;
using short4v = __attribute__((ext_vector_type(4))) short;
using f32x4   = __attribute__((ext_vector_type(4))) float;

// workspace byte offsets
#define WS_W1P 0          // 1024x64 bf16 packed A-frags (131072 B)
#define WS_W2P 131072     // 64x1024 bf16 packed A-frags (131072 B)
#define WS_GP  262144     // 64x64 bf16 packed A-frags (8192 B)
#define WS_U   270336     // 64 f32  (u = b2 @ W1k)
#define WS_VST 270592     // 24x64 f32 affine stage consts (6144 B)
#define WS_HU  276736     // 64 f32  (h*u) (256 B)

// LDS (block-shared, total 24320 B)
#define L_H0A  0          // group A: H ping [16][72] bf16, pitch 144
#define L_H1A  2304
#define L_HBA  4608
#define L_H0B  6912       // group B buffers
#define L_H1B  9216
#define L_HBB  11520
#define L_VST  13824      // VST staged (6144)
#define L_HU   19968      // h*u staged (256)
#define L_B2   20224      // b2 staged f32[1024] (4096)
#define LDS_TOTAL 24320
#define HP 144

// LDS-only barrier: order LDS ops, do NOT drain vmcnt (global loads stay
// in flight across barriers).
#define BAR() asm volatile("s_waitcnt lgkmcnt(0)\n\ts_barrier" ::: "memory")

__device__ __forceinline__ short f2bf(float f) {   // RNE via HW cvt
    __hip_bfloat16 h = __float2bfloat16(f);
    short s;
    __builtin_memcpy(&s, &h, 2);
    return s;
}
__device__ __forceinline__ float ftanh(float x) {
    x = fminf(fmaxf(x, -10.f), 10.f);
    float e = __expf(2.f * x);
    return __fdividef(e - 1.f, e + 1.f);
}

// ---------------- prep: pack weights + precompute stage tables ----------------
__global__ void k_prep(const float* __restrict__ W1, const float* __restrict__ W2,
                       const float* __restrict__ b1, const float* __restrict__ b2,
                       short* __restrict__ W1P, short* __restrict__ W2P,
                       short* __restrict__ GP, float* __restrict__ U,
                       float* __restrict__ VST, float* __restrict__ HU) {
    __shared__ float red[4][64];
    int b = blockIdx.x;
    int t = threadIdx.x;           // 256 threads
    int l = t & 63, q4 = t >> 6;
    if (b < 32) {                  // W1P: kk = b, c = q4
        int kk = b, c = q4;
        int col = c * 16 + (l & 15);
        int kb = kk * 32 + ((l >> 4) << 3);
        short8 v;
        #pragma unroll
        for (int i = 0; i < 8; ++i) v[i] = f2bf(W1[(kb + i) * HID + col]);
        *(short8*)(W1P + (((kk * 4 + c) * 64) + l) * 8) = v;
    } else if (b < 64) {           // W2P: unit = (b-32)*4 + q4
        int unit = (b - 32) * 4 + q4;
        int kk2 = unit >> 6, ct = unit & 63;
        int col = ct * 16 + (l & 15);
        int kb = kk2 * 32 + ((l >> 4) << 3);
        short8 v;
        #pragma unroll
        for (int i = 0; i < 8; ++i) v[i] = f2bf(W2[(kb + i) * DM + col]);
        *(short8*)(W2P + (((kk2 * 64 + ct) * 64) + l) * 8) = v;
    } else if (b < 128) {          // G[j][i] = sum_d W2[j][d]*W1[d][i]; j = b-64
        int j = b - 64;
        float acc = 0.f;
        #pragma unroll 8
        for (int d = q4 * 256; d < q4 * 256 + 256; ++d)
            acc += W2[j * DM + d] * W1[d * HID + l];
        red[q4][l] = acc;
        __syncthreads();
        if (t < 64) {
            float a = red[0][l] + red[1][l] + red[2][l] + red[3][l];
            int kk = j >> 5, lk = (j >> 3) & 3, ii = j & 7, c = l >> 4, lo = l & 15;
            GP[(((kk * 4 + c) * 64) + lk * 16 + lo) * 8 + ii] = f2bf(a);
        }
    } else {                       // u = b2@W1k, HU = h*u, VST table
        float acc = 0.f;
        #pragma unroll 8
        for (int d = q4 * 256; d < q4 * 256 + 256; ++d)
            acc += b2[d] * W1[d * HID + l];
        red[q4][l] = acc;
        __syncthreads();
        if (t < 64) {
            float uu = red[0][l] + red[1][l] + red[2][l] + red[3][l];
            U[l] = uu;
            HU[l] = RSTEP * uu;
            float b1l = b1[l];
            float wtl = W1[DM * HID + l];        // time row of W1
            #pragma unroll
            for (int s6 = 0; s6 < 6; ++s6) {
                float ts = RSTEP * (float)s6;
                float tm = ts + 0.5f * RSTEP;
                float vmid = b1l + tm * wtl + 0.5f * RSTEP * uu;
                VST[(s6 * 4 + 0) * 64 + l] = b1l + ts * wtl;
                VST[(s6 * 4 + 1) * 64 + l] = vmid;
                VST[(s6 * 4 + 2) * 64 + l] = vmid;
                VST[(s6 * 4 + 3) * 64 + l] = b1l + (ts + RSTEP) * wtl + RSTEP * uu;
            }
        }
    }
}

// dual-group epilogue macros (internals epc_-prefixed — R15 capture lesson).
// EPL2: 4 W2P frags for ct pair P,P+1 (shared by BOTH row-groups).
// EPC2: 8 MFMA (2 groups x 2 ct), x loads issued inside (L2-resident).
#define EPL2(Wa,Wb,Wc,Wd,P) \
    Wa = w2p8[(P) * 64 + lane];        Wb = w2p8[((P) + 64) * 64 + lane]; \
    Wc = w2p8[((P) + 1) * 64 + lane];  Wd = w2p8[((P) + 65) * 64 + lane];

#define EPC2(Wa,Wb,Wc,Wd,P) { \
    f32x4 epc_xa0 = *(const f32x4*)(xrowA + (P) * 16 + (hq << 2)); \
    f32x4 epc_xa1 = *(const f32x4*)(xrowA + ((P) + 1) * 16 + (hq << 2)); \
    f32x4 epc_xb0 = *(const f32x4*)(xrowB + (P) * 16 + (hq << 2)); \
    f32x4 epc_xb1 = *(const f32x4*)(xrowB + ((P) + 1) * 16 + (hq << 2)); \
    f32x4 accA0 = (f32x4){0.f,0.f,0.f,0.f}, accA1 = accA0, accB0 = accA0, accB1 = accA0; \
    accA0 = __builtin_amdgcn_mfma_f32_16x16x32_bf16(Wa, sbA0, accA0, 0, 0, 0); \
    accA0 = __builtin_amdgcn_mfma_f32_16x16x32_bf16(Wb, sbA1, accA0, 0, 0, 0); \
    accA1 = __builtin_amdgcn_mfma_f32_16x16x32_bf16(Wc, sbA0, accA1, 0, 0, 0); \
    accA1 = __builtin_amdgcn_mfma_f32_16x16x32_bf16(Wd, sbA1, accA1, 0, 0, 0); \
    accB0 = __builtin_amdgcn_mfma_f32_16x16x32_bf16(Wa, sbB0, accB0, 0, 0, 0); \
    accB0 = __builtin_amdgcn_mfma_f32_16x16x32_bf16(Wb, sbB1, accB0, 0, 0, 0); \
    accB1 = __builtin_amdgcn_mfma_f32_16x16x32_bf16(Wc, sbB0, accB1, 0, 0, 0); \
    accB1 = __builtin_amdgcn_mfma_f32_16x16x32_bf16(Wd, sbB1, accB1, 0, 0, 0); \
    f32x4 epc_bv0 = *(const f32x4*)(smem + L_B2 + ((P) * 16 + (hq << 2)) * 4); \
    f32x4 epc_bv1 = *(const f32x4*)(smem + L_B2 + (((P) + 1) * 16 + (hq << 2)) * 4); \
    f32x4 epc_nA0, epc_nA1, epc_nB0, epc_nB1; \
    for (int j = 0; j < 4; ++j) { \
        epc_nA0[j] = epc_xa0[j] + accA0[j] + epc_bv0[j]; \
        epc_nA1[j] = epc_xa1[j] + accA1[j] + epc_bv1[j]; \
        epc_nB0[j] = epc_xb0[j] + accB0[j] + epc_bv0[j]; \
        epc_nB1[j] = epc_xb1[j] + accB1[j] + epc_bv1[j]; } \
    *(f32x4*)(orowA + (P) * 16 + (hq << 2)) = epc_nA0; \
    *(f32x4*)(orowA + ((P) + 1) * 16 + (hq << 2)) = epc_nA1; \
    *(f32x4*)(orowB + (P) * 16 + (hq << 2)) = epc_nB0; \
    *(f32x4*)(orowB + ((P) + 1) * 16 + (hq << 2)) = epc_nB1; }

// ---------------- fused RK4 neural-ODE kernel (dual row-group ILP) -----------
// Block: 256 thr (4 waves), TWO 16-row groups A/B, grid 512 (2 blocks/CU).
// Every latency link in the step-loop chain (ds_read -> MFMA -> tanh ->
// ds_write -> BAR) now has TWO independent per-wave chains (A and B)
// interleaved instruction-by-instruction; barriers per unit work halve;
// prologue/epilogue memory depth doubles; epilogue W2P frags are loaded
// once and shared by both groups (halves weight loads per row).
// Algebra unchanged (R12/R13-proven): incremental sz + deferred z.
// Wave w owns hid c-tile w for both groups' stages; H0/H1/HB x{A,B}
// triple-buffers, 4 lgkm-only BARs/step (R16's race-free schedule).
// ALLOCATION: amdgpu_waves_per_eu(2,4) (16-round ledger). Peak ~100 regs.
__global__ __launch_bounds__(256) __attribute__((amdgpu_waves_per_eu(2, 4)))
void k_ode(
        const float* __restrict__ X, const float* __restrict__ b2,
        const short* __restrict__ W1P, const short* __restrict__ W2P,
        const short* __restrict__ GP, const float* __restrict__ VST,
        const float* __restrict__ HU, float* __restrict__ OUT) {
    extern __shared__ char smem[];
    const int t = threadIdx.x;
    const int lane = t & 63;
    const int w = t >> 6;                    // 0..3 = c-tile in stages
    const int hq = lane >> 4;
    const int l15 = lane & 15;
    const int hcol0 = w * 16 + hq * 4;       // stage hid-col base
    const size_t row0 = (size_t)blockIdx.x * 32;
    const float* xrowA = X + (row0 + l15) * DM;
    const float* xrowB = X + (row0 + 16 + l15) * DM;

    // ---- stage consts into LDS (b2, VST, HU) ----
    *(f32x4*)(smem + L_B2 + t * 16) = *(const f32x4*)(b2 + t * 4);
    *(f32x4*)(smem + L_VST + t * 16) = *(const f32x4*)(VST + t * 4);
    if (t < 128)
        *(f32x4*)(smem + L_VST + 4096 + t * 16) = *(const f32x4*)(VST + 1024 + t * 4);
    else if (t < 144)
        *(f32x4*)(smem + L_HU + (t - 128) * 16) = *(const f32x4*)(HU + (t - 128) * 4);

    // pinned G A-frags for own c-tile
    short8 gf0 = *(const short8*)(GP + (w * 64 + lane) * 8);
    short8 gf1 = *(const short8*)(GP + ((4 + w) * 64 + lane) * 8);

    // ---- prologue GEMM1 (once): szA/szB = x @ W1k (c-tile w);
    // 8 alternating 4-kk bursts -> 16 loads in flight, 2 MFMA chains
    f32x4 szA = (f32x4){0.f, 0.f, 0.f, 0.f};
    f32x4 szB = (f32x4){0.f, 0.f, 0.f, 0.f};
    {
        const short8* wp = (const short8*)W1P;
        #pragma unroll
        for (int Bb = 0; Bb < 8; ++Bb) {
            f32x4 loA[4], hiA[4], loB[4], hiB[4];
            #pragma unroll
            for (int i = 0; i < 4; ++i) {
                const float* xp = xrowA + ((Bb * 4 + i) << 5) + (hq << 3);
                loA[i] = *(const f32x4*)(xp);
                hiA[i] = *(const f32x4*)(xp + 4);
            }
            #pragma unroll
            for (int i = 0; i < 4; ++i) {
                const float* xp = xrowB + ((Bb * 4 + i) << 5) + (hq << 3);
                loB[i] = *(const f32x4*)(xp);
                hiB[i] = *(const f32x4*)(xp + 4);
            }
            #pragma unroll
            for (int i = 0; i < 4; ++i) {
                int kk = Bb * 4 + i;
                short8 zfA, zfB;
                #pragma unroll
                for (int j = 0; j < 4; ++j) {
                    zfA[j] = f2bf(loA[i][j]); zfA[4 + j] = f2bf(hiA[i][j]);
                    zfB[j] = f2bf(loB[i][j]); zfB[4 + j] = f2bf(hiB[i][j]);
                }
                short8 wf = wp[(kk * 4 + w) * 64 + lane];
                szA = __builtin_amdgcn_mfma_f32_16x16x32_bf16(wf, zfA, szA, 0, 0, 0);
                szB = __builtin_amdgcn_mfma_f32_16x16x32_bf16(wf, zfB, szB, 0, 0, 0);
            }
        }
    }
    BAR();   // covers LDS const staging

    f32x4 ssumA = (f32x4){0.f, 0.f, 0.f, 0.f};
    f32x4 ssumB = (f32x4){0.f, 0.f, 0.f, 0.f};

    for (int s = 0; s < NSTEP; ++s) {
        f32x4 hsumA, hsumB;

        // eval 0: H = tanh(sz + VST[s][0]) -> H0{A,B}
        {
            f32x4 vst = *(const f32x4*)(smem + L_VST + (s * 4 + 0) * 256 + hcol0 * 4);
            short4v hcA, hcB;
            #pragma unroll
            for (int j = 0; j < 4; ++j) {
                float hA = ftanh(szA[j] + vst[j]);
                float hB = ftanh(szB[j] + vst[j]);
                hsumA[j] = hA; hsumB[j] = hB;
                hcA[j] = f2bf(hA); hcB[j] = f2bf(hB);
            }
            *(short4v*)(smem + L_H0A + l15 * HP + hcol0 * 2) = hcA;
            *(short4v*)(smem + L_H0B + l15 * HP + hcol0 * 2) = hcB;
        }
        BAR();

        // evals 1..3: dd = H@G; H' = tanh(sz + c_e*dd + VST[s][e]); A,B twin chains
        #pragma unroll
        for (int e = 1; e < 4; ++e) {
            const float ce = (e == 3) ? RSTEP : (0.5f * RSTEP);
            const float we = (e == 3) ? 1.f : 2.f;
            const int rbA = (e == 2) ? L_H1A : L_H0A;
            const int wbA = (e == 1) ? L_H1A : ((e == 2) ? L_H0A : L_HBA);
            const int rbB = (e == 2) ? L_H1B : L_H0B;
            const int wbB = (e == 1) ? L_H1B : ((e == 2) ? L_H0B : L_HBB);

            short8 hfA0 = *(const short8*)(smem + rbA + l15 * HP + (hq << 4));
            short8 hfA1 = *(const short8*)(smem + rbA + l15 * HP + 64 + (hq << 4));
            short8 hfB0 = *(const short8*)(smem + rbB + l15 * HP + (hq << 4));
            short8 hfB1 = *(const short8*)(smem + rbB + l15 * HP + 64 + (hq << 4));
            f32x4 ddA = (f32x4){0.f, 0.f, 0.f, 0.f};
            f32x4 ddB = (f32x4){0.f, 0.f, 0.f, 0.f};
            ddA = __builtin_amdgcn_mfma_f32_16x16x32_bf16(gf0, hfA0, ddA, 0, 0, 0);
            ddB = __builtin_amdgcn_mfma_f32_16x16x32_bf16(gf0, hfB0, ddB, 0, 0, 0);
            ddA = __builtin_amdgcn_mfma_f32_16x16x32_bf16(gf1, hfA1, ddA, 0, 0, 0);
            ddB = __builtin_amdgcn_mfma_f32_16x16x32_bf16(gf1, hfB1, ddB, 0, 0, 0);
            f32x4 vst = *(const f32x4*)(smem + L_VST + (s * 4 + e) * 256 + hcol0 * 4);
            short4v hcA, hcB;
            #pragma unroll
            for (int j = 0; j < 4; ++j) {
                float hA = ftanh(szA[j] + ce * ddA[j] + vst[j]);
                float hB = ftanh(szB[j] + ce * ddB[j] + vst[j]);
                hsumA[j] += we * hA; hsumB[j] += we * hB;
                if (e < 3) {
                    hcA[j] = f2bf(hA); hcB[j] = f2bf(hB);
                } else {
                    ssumA[j] += hsumA[j] * (RSTEP / 6.f);
                    ssumB[j] += hsumB[j] * (RSTEP / 6.f);
                    hcA[j] = (s < NSTEP - 1) ? f2bf(hsumA[j] * (RSTEP / 6.f)) : f2bf(ssumA[j]);
                    hcB[j] = (s < NSTEP - 1) ? f2bf(hsumB[j] * (RSTEP / 6.f)) : f2bf(ssumB[j]);
                }
            }
            *(short4v*)(smem + wbA + l15 * HP + hcol0 * 2) = hcA;
            *(short4v*)(smem + wbB + l15 * HP + hcol0 * 2) = hcB;
            BAR();
        }

        // sz update: sz += Hb@G + h*u (twin chains; race-free as R16)
        if (s < NSTEP - 1) {
            short8 hbA0 = *(const short8*)(smem + L_HBA + l15 * HP + (hq << 4));
            short8 hbA1 = *(const short8*)(smem + L_HBA + l15 * HP + 64 + (hq << 4));
            short8 hbB0 = *(const short8*)(smem + L_HBB + l15 * HP + (hq << 4));
            short8 hbB1 = *(const short8*)(smem + L_HBB + l15 * HP + 64 + (hq << 4));
            f32x4 dA = (f32x4){0.f, 0.f, 0.f, 0.f};
            f32x4 dB = (f32x4){0.f, 0.f, 0.f, 0.f};
            dA = __builtin_amdgcn_mfma_f32_16x16x32_bf16(gf0, hbA0, dA, 0, 0, 0);
            dB = __builtin_amdgcn_mfma_f32_16x16x32_bf16(gf0, hbB0, dB, 0, 0, 0);
            dA = __builtin_amdgcn_mfma_f32_16x16x32_bf16(gf1, hbA1, dA, 0, 0, 0);
            dB = __builtin_amdgcn_mfma_f32_16x16x32_bf16(gf1, hbB1, dB, 0, 0, 0);
            f32x4 hu4 = *(const f32x4*)(smem + L_HU + hcol0 * 4);
            #pragma unroll
            for (int j = 0; j < 4; ++j) {
                szA[j] += dA[j] + hu4[j];
                szB[j] += dB[j] + hu4[j];
            }
        }
    }

    // ---- epilogue: z_T = x + S@W2 + b2 for BOTH groups; wave w -> ct
    // [w*16,+16); W2P frags shared across groups; 2-ct ping-pong.
    {
        short8 sbA0 = *(const short8*)(smem + L_HBA + l15 * HP + (hq << 4));
        short8 sbA1 = *(const short8*)(smem + L_HBA + l15 * HP + 64 + (hq << 4));
        short8 sbB0 = *(const short8*)(smem + L_HBB + l15 * HP + (hq << 4));
        short8 sbB1 = *(const short8*)(smem + L_HBB + l15 * HP + 64 + (hq << 4));
        const short8* w2p8 = (const short8*)W2P;
        float* orowA = OUT + (row0 + l15) * DM;
        float* orowB = OUT + (row0 + 16 + l15) * DM;
        const int ctbase = w * 16;

        short8 wA0, wA1, wA2, wA3;
        short8 wB0, wB1, wB2, wB3;
        EPL2(wA0, wA1, wA2, wA3, ctbase)
        #pragma unroll
        for (int p = 0; p < 16; p += 4) {
            EPL2(wB0, wB1, wB2, wB3, ctbase + p + 2)
            EPC2(wA0, wA1, wA2, wA3, ctbase + p)
            if (p + 4 < 16) { EPL2(wA0, wA1, wA2, wA3, ctbase + p + 4) }
            EPC2(wB0, wB1, wB2, wB3, ctbase + p + 2)
        }
    }
}

extern "C" void kernel_launch(void* const* d_in, const int* in_sizes, int n_in,
                              void* d_out, int out_size, void* d_ws, size_t ws_size,
                              hipStream_t stream) {
    (void)in_sizes; (void)n_in; (void)out_size; (void)ws_size;
    const float* X  = (const float*)d_in[0];
    const float* W1 = (const float*)d_in[1];
    const float* b1 = (const float*)d_in[2];
    const float* W2 = (const float*)d_in[3];
    const float* b2 = (const float*)d_in[4];
    float* OUT = (float*)d_out;
    short* W1P = (short*)((char*)d_ws + WS_W1P);
    short* W2P = (short*)((char*)d_ws + WS_W2P);
    short* GP  = (short*)((char*)d_ws + WS_GP);
    float* U   = (float*)((char*)d_ws + WS_U);
    float* VST = (float*)((char*)d_ws + WS_VST);
    float* HU  = (float*)((char*)d_ws + WS_HU);

    k_prep<<<129, 256, 0, stream>>>(W1, W2, b1, b2, W1P, W2P, GP, U, VST, HU);
    k_ode<<<512, 256, LDS_TOTAL, stream>>>(X, b2, W1P, W2P, GP, VST, HU, OUT);
}